// Round 4
// baseline (3655.999 us; speedup 1.0000x reference)
//
#include <hip/hip_runtime.h>
#include <hip/hip_bf16.h>

// HGNNP_GCN + ClusterNet forward, MI355X (round 4 = resubmit after two infra
// failures: runtime dtype detection). The device float dtype (f32 vs
// bf16-flavor) is detected on-device from x's bit patterns; all external
// loads/stores branch on the uniform flag.

#define NN   50000   // nodes
#define EE   800000  // directed edges
#define NINC 200000  // incidence entries
#define NEH  10000   // hyperedges
#define KCL  10      // clusters

// output element offsets (flat concat: mu | r | embeds | dist)
#define MU_OFF  0
#define R_OFF   640
#define EMB_OFF 500640
#define D_OFF   3700640

typedef __hip_bfloat16 bf16;

__device__ __forceinline__ float b2f(bf16 v){ return __bfloat162float(v); }
__device__ __forceinline__ bf16 f2b(float f){
  unsigned u = __float_as_uint(f);
  unsigned r = (u + 0x7fffu + ((u >> 16) & 1u)) >> 16;  // RNE to bf16
  bf16 h;
  reinterpret_cast<unsigned short&>(h) = (unsigned short)r;
  return h;
}
// external-float load/store, dtype chosen by uniform runtime flag
__device__ __forceinline__ float ldf(const void* p, size_t i, int isbf){
  return isbf ? b2f(((const bf16*)p)[i]) : ((const float*)p)[i];
}
__device__ __forceinline__ void stf(void* p, size_t i, float v, int isbf){
  if (isbf) ((bf16*)p)[i] = f2b(v);
  else      ((float*)p)[i] = v;
}

// ---------------- dtype detector ----------------
// Read x as bf16: if x is really f32, odd elements are f32 low-halves with
// uniform random exponents -> many with exp >= 0xEF (|v|>=2^112). True bf16
// N(0,1) data never exceeds exp ~0x90.
__global__ void k_detect(const unsigned short* __restrict__ xr, int* flag){
  __shared__ int bad;
  if (threadIdx.x == 0) bad = 0;
  __syncthreads();
  for (int i = threadIdx.x; i < 4096; i += 256){
    int e = (xr[i] >> 7) & 0xFF;
    if (e >= 0xEF) bad = 1;     // benign race: all writers store 1
  }
  __syncthreads();
  if (threadIdx.x == 0) *flag = bad ? 0 : 1;   // 1 = bf16, 0 = f32
}

// ---------------- degrees ----------------
__global__ void k_deg_init(float* deg, float* cntv, float* cnte){
  int i = blockIdx.x*256 + threadIdx.x;
  if (i < NN){ deg[i] = 1.0f; cntv[i] = 0.0f; }  // deg starts at 1 (self-loop)
  if (i < NEH) cnte[i] = 0.0f;
}

__global__ void k_deg_count(const int* __restrict__ dst, const int* __restrict__ hv,
                            const int* __restrict__ he,
                            float* deg, float* cntv, float* cnte){
  int i = blockIdx.x*256 + threadIdx.x;
  if (i < EE) unsafeAtomicAdd(&deg[dst[i]], 1.0f);   // integer-valued: exact
  if (i < NINC){
    unsafeAtomicAdd(&cntv[hv[i]], 1.0f);
    unsafeAtomicAdd(&cnte[he[i]], 1.0f);
  }
}

__global__ void k_deg_final(float* deg, float* dinv, float* invd,
                            float* cntv, float* cnte){
  int i = blockIdx.x*256 + threadIdx.x;
  if (i < NN){
    float d = deg[i];
    dinv[i] = rsqrtf(d);
    invd[i] = 1.0f / d;
    cntv[i] = 1.0f / fmaxf(cntv[i], 1.0f);   // -> inv_v in place
  }
  if (i < NEH) cnte[i] = 1.0f / fmaxf(cnte[i], 1.0f);  // -> inv_e in place
}

// ---------------- GEMM: C[M][NCOL] = A[M][KDIM] @ W[KDIM][NCOL] (+bias,relu) ----------------
// AEXT: A is an external float tensor (dtype per flag); else internal f32.
template<int KDIM, int NCOL, bool AEXT>
__global__ __launch_bounds__(256) void k_gemm(const void* __restrict__ Av,
    const void* __restrict__ W, const void* __restrict__ bias,
    float* __restrict__ C, int M, int relu, const int* __restrict__ flag)
{
  constexpr int BM = 32, KC = 64;
  constexpr int CG  = NCOL/4;     // col groups of 4 (float4)
  constexpr int RS  = 256/CG;     // row slots
  constexpr int RPT = BM/RS;      // rows per thread
  __shared__ float Ws[KC][NCOL];
  __shared__ float As[BM][KC+1];  // +1 pad: kills bank conflicts
  const int isbf = flag[0];
  const int tid = threadIdx.x;
  const int cg = tid % CG, rs = tid / CG;
  const int row0 = blockIdx.x * BM;
  float acc[RPT][4];
  #pragma unroll
  for (int r=0;r<RPT;r++){ acc[r][0]=acc[r][1]=acc[r][2]=acc[r][3]=0.f; }

  for (int kk=0; kk<KDIM; kk+=KC){
    for (int j=tid; j<KC*NCOL; j+=256)
      Ws[j/NCOL][j%NCOL] = ldf(W, (size_t)(kk + j/NCOL)*NCOL + (j%NCOL), isbf);
    for (int j=tid; j<BM*KC; j+=256){
      int r = j >> 6, k = j & 63;
      int row = row0 + r;
      float v = 0.f;
      if (row < M){
        if (AEXT) v = ldf(Av, (size_t)row*KDIM + kk + k, isbf);
        else      v = ((const float*)Av)[(size_t)row*KDIM + kk + k];
      }
      As[r][k] = v;
    }
    __syncthreads();
    #pragma unroll 8
    for (int k=0;k<KC;k++){
      float4 w = *(const float4*)&Ws[k][cg*4];
      #pragma unroll
      for (int rr=0; rr<RPT; rr++){
        float a = As[rs + rr*RS][k];
        acc[rr][0] = fmaf(a, w.x, acc[rr][0]);
        acc[rr][1] = fmaf(a, w.y, acc[rr][1]);
        acc[rr][2] = fmaf(a, w.z, acc[rr][2]);
        acc[rr][3] = fmaf(a, w.w, acc[rr][3]);
      }
    }
    __syncthreads();
  }
  float4 bv = make_float4(0.f,0.f,0.f,0.f);
  if (bias){
    bv.x = ldf(bias, cg*4+0, isbf); bv.y = ldf(bias, cg*4+1, isbf);
    bv.z = ldf(bias, cg*4+2, isbf); bv.w = ldf(bias, cg*4+3, isbf);
  }
  #pragma unroll
  for (int rr=0; rr<RPT; rr++){
    int row = row0 + rs + rr*RS;
    if (row < M){
      float o0=acc[rr][0]+bv.x, o1=acc[rr][1]+bv.y;
      float o2=acc[rr][2]+bv.z, o3=acc[rr][3]+bv.w;
      if (relu){ o0=fmaxf(o0,0.f); o1=fmaxf(o1,0.f); o2=fmaxf(o2,0.f); o3=fmaxf(o3,0.f); }
      *(float4*)&C[(size_t)row*NCOL + cg*4] = make_float4(o0,o1,o2,o3);
    }
  }
}

// ---------------- GCN propagation ----------------
template<int F>
__global__ void k_selfloop(const float* __restrict__ h, const float* __restrict__ invd,
                           float* __restrict__ out){
  int i = blockIdx.x*256 + threadIdx.x;
  if (i >= NN*F) return;
  out[i] = h[i]*invd[i/F];
}

template<int F>
__global__ void k_gcn_scatter(const int* __restrict__ src, const int* __restrict__ dst,
                              const float* __restrict__ dinv, const float* __restrict__ h,
                              float* __restrict__ out){
  constexpr int TPE = F/4;
  int t = blockIdx.x*256 + threadIdx.x;
  int e = t / TPE, l = t % TPE;
  if (e >= EE) return;
  int s = src[e], d = dst[e];
  float w = dinv[s]*dinv[d];
  const float4 v = *(const float4*)&h[(size_t)s*F + l*4];
  float* op = &out[(size_t)d*F + l*4];
  unsafeAtomicAdd(op+0, v.x*w);
  unsafeAtomicAdd(op+1, v.y*w);
  unsafeAtomicAdd(op+2, v.z*w);
  unsafeAtomicAdd(op+3, v.w*w);
}

template<int F>
__global__ void k_bias_act(float* __restrict__ b, const void* __restrict__ bias,
                           int relu, const int* __restrict__ flag){
  int i = blockIdx.x*256 + threadIdx.x;
  if (i >= NN*F) return;
  float v = b[i] + ldf(bias, i & (F-1), flag[0]);
  if (relu) v = fmaxf(v, 0.f);
  b[i] = v;
}

// ---------------- hypergraph propagation ----------------
template<int F>
__global__ void k_hg_ve(const int* __restrict__ hv, const int* __restrict__ he,
                        const float* __restrict__ h, float* __restrict__ ef){
  constexpr int TPE = F/4;
  int t = blockIdx.x*256 + threadIdx.x;
  int j = t / TPE, l = t % TPE;
  if (j >= NINC) return;
  int v = hv[j], e = he[j];
  const float4 val = *(const float4*)&h[(size_t)v*F + l*4];
  float* op = &ef[(size_t)e*F + l*4];
  unsafeAtomicAdd(op+0, val.x);
  unsafeAtomicAdd(op+1, val.y);
  unsafeAtomicAdd(op+2, val.z);
  unsafeAtomicAdd(op+3, val.w);
}

template<int F>
__global__ void k_hg_ev(const int* __restrict__ hv, const int* __restrict__ he,
                        const float* __restrict__ ef, float* __restrict__ vout){
  constexpr int TPE = F/4;
  int t = blockIdx.x*256 + threadIdx.x;
  int j = t / TPE, l = t % TPE;
  if (j >= NINC) return;
  int v = hv[j], e = he[j];
  const float4 val = *(const float4*)&ef[(size_t)e*F + l*4];
  float* op = &vout[(size_t)v*F + l*4];
  unsafeAtomicAdd(op+0, val.x);
  unsafeAtomicAdd(op+1, val.y);
  unsafeAtomicAdd(op+2, val.z);
  unsafeAtomicAdd(op+3, val.w);
}

template<int F>
__global__ void k_scale_rows(float* __restrict__ b, const float* __restrict__ s,
                             int nrows, int relu){
  int i = blockIdx.x*256 + threadIdx.x;
  if (i >= nrows*F) return;
  float v = b[i]*s[i/F];
  if (relu) v = fmaxf(v, 0.f);
  b[i] = v;
}

// ---------------- embeds + row normalize ----------------
__global__ void k_embeds(const float* __restrict__ x2, const float* __restrict__ x4,
                         void* __restrict__ out, float* __restrict__ data,
                         const int* __restrict__ flag){
  int row  = blockIdx.x*4 + (threadIdx.x >> 6);
  int lane = threadIdx.x & 63;
  if (row >= NN) return;
  size_t idx = (size_t)row*64 + lane;
  float v = 0.5f*(x2[idx] + x4[idx]);
  float ss = v*v;
  #pragma unroll
  for (int off=32; off>0; off>>=1) ss += __shfl_xor(ss, off);
  float inv = rsqrtf(ss);
  data[idx] = v*inv;
  stf(out, EMB_OFF + idx, v, flag[0]);
}

// ---------------- clustering ----------------
__global__ void k_mu_init(const float* __restrict__ data, float* __restrict__ mu){
  int p = blockIdx.x*256 + threadIdx.x;
  if (p >= KCL*64) return;
  int k = p >> 6, f = p & 63;
  mu[p] = data[(size_t)k*(NN/KCL)*64 + f];   // init_idx = k*(N//K)
}

__global__ __launch_bounds__(128) void k_cluster_accum(const float* __restrict__ data,
    const float* __restrict__ mu, float* csum, float* cr, const int* nit, int iter)
{
  if (iter >= nit[0]) return;
  __shared__ float dt[128][65];
  __shared__ float rl[128][KCL];
  __shared__ float ms[KCL*64];
  int tid = threadIdx.x;
  int rowbase = blockIdx.x*128;
  for (int j=tid; j<KCL*64; j+=128) ms[j] = mu[j];
  for (int j=tid; j<128*64; j+=128){
    int rr = j>>6, f = j&63;
    int row = rowbase + rr;
    dt[rr][f] = (row<NN) ? data[(size_t)row*64+f] : 0.f;
  }
  __syncthreads();
  {
    int row = rowbase + tid;
    float dot[KCL];
    #pragma unroll
    for (int k2=0;k2<KCL;k2++) dot[k2]=0.f;
    for (int f=0; f<64; f++){
      float a = dt[tid][f];
      #pragma unroll
      for (int k2=0;k2<KCL;k2++) dot[k2] = fmaf(a, ms[k2*64+f], dot[k2]);
    }
    float m = -1e30f;
    #pragma unroll
    for (int k2=0;k2<KCL;k2++) m = fmaxf(m, 5.0f*dot[k2]);
    float s = 0.f, ev[KCL];
    #pragma unroll
    for (int k2=0;k2<KCL;k2++){ ev[k2] = expf(5.0f*dot[k2]-m); s += ev[k2]; }
    float inv = 1.0f/s;
    #pragma unroll
    for (int k2=0;k2<KCL;k2++) rl[tid][k2] = (row<NN) ? ev[k2]*inv : 0.f;
  }
  __syncthreads();
  for (int p=tid; p<KCL*64; p+=128){
    int k2 = p>>6, f = p&63;
    float acc = 0.f;
    for (int r2=0;r2<128;r2++) acc += rl[r2][k2]*dt[r2][f];
    unsafeAtomicAdd(&csum[p], acc);
  }
  if (tid < KCL){
    float acc = 0.f;
    for (int r2=0;r2<128;r2++) acc += rl[r2][tid];
    unsafeAtomicAdd(&cr[tid], acc);
  }
}

__global__ void k_mu_update(float* mu, float* csum, float* cr, const int* nit, int iter){
  if (iter >= nit[0]) return;
  int p = threadIdx.x;        // launched with exactly 640 threads
  float c = csum[p];
  float r = cr[p>>6];
  __syncthreads();
  mu[p] = c / r;
  csum[p] = 0.f;
  if (p < KCL) cr[p] = 0.f;
}

__global__ __launch_bounds__(128) void k_cluster_final(const float* __restrict__ data,
    const float* __restrict__ mu, void* __restrict__ out, const int* __restrict__ flag)
{
  __shared__ float dt[128][65];
  __shared__ float ms[KCL*64];
  int tid = threadIdx.x;
  int rowbase = blockIdx.x*128;
  for (int j=tid; j<KCL*64; j+=128) ms[j] = mu[j];
  for (int j=tid; j<128*64; j+=128){
    int rr = j>>6, f = j&63;
    int row = rowbase + rr;
    dt[rr][f] = (row<NN) ? data[(size_t)row*64+f] : 0.f;
  }
  __syncthreads();
  int row = rowbase + tid;
  if (row >= NN) return;
  int isbf = flag[0];
  float dot[KCL];
  #pragma unroll
  for (int k2=0;k2<KCL;k2++) dot[k2]=0.f;
  for (int f=0; f<64; f++){
    float a = dt[tid][f];
    #pragma unroll
    for (int k2=0;k2<KCL;k2++) dot[k2] = fmaf(a, ms[k2*64+f], dot[k2]);
  }
  float m = -1e30f;
  #pragma unroll
  for (int k2=0;k2<KCL;k2++) m = fmaxf(m, 5.0f*dot[k2]);
  float s = 0.f, ev[KCL];
  #pragma unroll
  for (int k2=0;k2<KCL;k2++){ ev[k2] = expf(5.0f*dot[k2]-m); s += ev[k2]; }
  float inv = 1.0f/s;
  #pragma unroll
  for (int k2=0;k2<KCL;k2++){
    stf(out, (size_t)D_OFF + (size_t)row*KCL + k2, dot[k2],     isbf);
    stf(out, (size_t)R_OFF + (size_t)row*KCL + k2, ev[k2]*inv,  isbf);
  }
}

__global__ void k_mu_out(const float* __restrict__ mu, void* __restrict__ out,
                         const int* __restrict__ flag){
  int p = blockIdx.x*256 + threadIdx.x;
  if (p < KCL*64) stf(out, MU_OFF + p, mu[p], flag[0]);
}

// ---------------- launch ----------------
extern "C" void kernel_launch(void* const* d_in, const int* in_sizes, int n_in,
                              void* d_out, int out_size, void* d_ws, size_t ws_size,
                              hipStream_t stream)
{
  const void* x   = d_in[0];
  const int*  ei  = (const int*)d_in[1];
  const int*  hv  = (const int*)d_in[2];
  const int*  he  = (const int*)d_in[3];
  const void* gW1 = d_in[4];
  const void* gb1 = d_in[5];
  const void* gW2 = d_in[6];
  const void* gb2 = d_in[7];
  const void* hW1 = d_in[8];
  const void* hb1 = d_in[9];
  const void* hW2 = d_in[10];
  const void* hb2 = d_in[11];
  const int*  nit = (const int*)d_in[12];

  float* ws = (float*)d_ws;
  size_t o = 0;
  float* B1   = ws + o; o += (size_t)NN*128;   // 25.6 MB
  float* B2   = ws + o; o += (size_t)NN*128;
  float* B3   = ws + o; o += (size_t)NN*128;
  float* B5   = ws + o; o += (size_t)NN*128;
  float* B4   = ws + o; o += (size_t)NEH*128;  // 5.12 MB
  float* deg  = ws + o; o += 50048;
  float* dinv = ws + o; o += 50048;
  float* invd = ws + o; o += 50048;
  float* invv = ws + o; o += 50048;
  float* inve = ws + o; o += 10048;
  float* mu   = ws + o; o += 640;
  float* csum = ws + o; o += 640;   // csum+cr contiguous: one memset
  float* cr   = ws + o; o += 64;
  int*   dflg = (int*)(ws + o); o += 16;

  const int* srcp = ei;
  const int* dstp = ei + EE;
  dim3 B(256);

  // dtype detection (uniform flag used by all external loads/stores)
  k_detect<<<dim3(1), B, 0, stream>>>((const unsigned short*)x, dflg);

  // degrees
  k_deg_init <<<dim3((NN+255)/256),  B, 0, stream>>>(deg, invv, inve);
  k_deg_count<<<dim3((EE+255)/256),  B, 0, stream>>>(dstp, hv, he, deg, invv, inve);
  k_deg_final<<<dim3((NN+255)/256),  B, 0, stream>>>(deg, dinv, invd, invv, inve);

  const int NB = (NN + 31)/32;
  // layer-1 GEMMs (external x)
  k_gemm<256,128,true><<<dim3(NB), B, 0, stream>>>(x, gW1, nullptr, B1, NN, 0, dflg);
  k_gemm<256,128,true><<<dim3(NB), B, 0, stream>>>(x, hW1, hb1,    B2, NN, 0, dflg);

  // GCN layer 1: D^-1/2 A D^-1/2 h + h/deg, then +b1, relu -> x1 in B3
  k_selfloop<128>   <<<dim3((NN*128+255)/256), B, 0, stream>>>(B1, invd, B3);
  k_gcn_scatter<128><<<dim3((EE*32+255)/256),  B, 0, stream>>>(srcp, dstp, dinv, B1, B3);
  k_bias_act<128>   <<<dim3((NN*128+255)/256), B, 0, stream>>>(B3, gb1, 1, dflg);

  // HGNNP layer 1: v->e mean, e->v mean, relu -> x3 in B5
  hipMemsetAsync(B4, 0, (size_t)NEH*128*4, stream);
  k_hg_ve<128>      <<<dim3((NINC*32+255)/256), B, 0, stream>>>(hv, he, B2, B4);
  k_scale_rows<128> <<<dim3((NEH*128+255)/256), B, 0, stream>>>(B4, inve, NEH, 0);
  hipMemsetAsync(B5, 0, (size_t)NN*128*4, stream);
  k_hg_ev<128>      <<<dim3((NINC*32+255)/256), B, 0, stream>>>(hv, he, B4, B5);
  k_scale_rows<128> <<<dim3((NN*128+255)/256),  B, 0, stream>>>(B5, invv, NN, 1);

  // GCN layer 2 -> x2 in B2
  k_gemm<128,64,false><<<dim3(NB), B, 0, stream>>>(B3, gW2, nullptr, B1, NN, 0, dflg);
  k_selfloop<64>    <<<dim3((NN*64+255)/256), B, 0, stream>>>(B1, invd, B2);
  k_gcn_scatter<64> <<<dim3((EE*16+255)/256), B, 0, stream>>>(srcp, dstp, dinv, B1, B2);
  k_bias_act<64>    <<<dim3((NN*64+255)/256), B, 0, stream>>>(B2, gb2, 0, dflg);

  // HGNNP layer 2 -> x4 in B3
  k_gemm<128,64,false><<<dim3(NB), B, 0, stream>>>(B5, hW2, hb2, B1, NN, 0, dflg);
  hipMemsetAsync(B4, 0, (size_t)NEH*64*4, stream);
  k_hg_ve<64>       <<<dim3((NINC*16+255)/256), B, 0, stream>>>(hv, he, B1, B4);
  k_scale_rows<64>  <<<dim3((NEH*64+255)/256),  B, 0, stream>>>(B4, inve, NEH, 0);
  hipMemsetAsync(B3, 0, (size_t)NN*64*4, stream);
  k_hg_ev<64>       <<<dim3((NINC*16+255)/256), B, 0, stream>>>(hv, he, B4, B3);
  k_scale_rows<64>  <<<dim3((NN*64+255)/256),   B, 0, stream>>>(B3, invv, NN, 0);

  // embeds (dtype-flag out) + normalized rows (f32 data -> B5, now free)
  k_embeds<<<dim3((NN+3)/4), B, 0, stream>>>(B2, B3, d_out, B5, dflg);

  // clustering: mu init, num_iter gated update steps, final assignment
  k_mu_init<<<dim3(3), B, 0, stream>>>(B5, mu);
  hipMemsetAsync(csum, 0, (640+64)*4, stream);
  const int CB = (NN + 127)/128;
  for (int it = 0; it < 4; ++it){   // gated by iter < *num_iter (setup: 1)
    k_cluster_accum<<<dim3(CB), dim3(128), 0, stream>>>(B5, mu, csum, cr, nit, it);
    k_mu_update    <<<dim3(1),  dim3(640), 0, stream>>>(mu, csum, cr, nit, it);
  }
  k_cluster_final<<<dim3(CB), dim3(128), 0, stream>>>(B5, mu, d_out, dflg);
  k_mu_out       <<<dim3(3),  B, 0, stream>>>(mu, d_out, dflg);
}

// Round 5
// 862.812 us; speedup vs baseline: 4.2373x; 4.2373x over previous
//
#include <hip/hip_runtime.h>
#include <hip/hip_bf16.h>

// HGNNP_GCN + ClusterNet forward, MI355X (round 5).
// R4 counters: k_gcn_scatter = 1340us, WRITE_SIZE 1.6GB (16B HBM RMW per f32
// atomic), VALUBusy 1.4% -> atomic-throughput-bound. This round: CSR built
// on-device (count/scan/fill), all aggregations become atomic-free gathers
// fused with selfloop/bias/relu/mean-scale. No float atomics remain in the
// graph pipeline.

#define NN   50000   // nodes
#define EE   800000  // directed edges
#define NINC 200000  // incidence entries
#define NEH  10000   // hyperedges
#define KCL  10      // clusters

// output element offsets (flat concat: mu | r | embeds | dist)
#define MU_OFF  0
#define R_OFF   640
#define EMB_OFF 500640
#define D_OFF   3700640

typedef __hip_bfloat16 bf16;

__device__ __forceinline__ float b2f(bf16 v){ return __bfloat162float(v); }
__device__ __forceinline__ bf16 f2b(float f){
  unsigned u = __float_as_uint(f);
  unsigned r = (u + 0x7fffu + ((u >> 16) & 1u)) >> 16;  // RNE to bf16
  bf16 h;
  reinterpret_cast<unsigned short&>(h) = (unsigned short)r;
  return h;
}
// external-float load/store, dtype chosen by uniform runtime flag
__device__ __forceinline__ float ldf(const void* p, size_t i, int isbf){
  return isbf ? b2f(((const bf16*)p)[i]) : ((const float*)p)[i];
}
__device__ __forceinline__ void stf(void* p, size_t i, float v, int isbf){
  if (isbf) ((bf16*)p)[i] = f2b(v);
  else      ((float*)p)[i] = v;
}

// ---------------- dtype detector ----------------
__global__ void k_detect(const unsigned short* __restrict__ xr, int* flag){
  __shared__ int bad;
  if (threadIdx.x == 0) bad = 0;
  __syncthreads();
  for (int i = threadIdx.x; i < 4096; i += 256){
    int e = (xr[i] >> 7) & 0xFF;
    if (e >= 0xEF) bad = 1;     // f32 low-halves have random exponents
  }
  __syncthreads();
  if (threadIdx.x == 0) *flag = bad ? 0 : 1;   // 1 = bf16, 0 = f32
}

// ---------------- CSR build: count / scan / fill ----------------
__global__ void k_cnt(const int* __restrict__ dst, const int* __restrict__ hv,
                      const int* __restrict__ he, int* cg, int* cv, int* ce){
  int i = blockIdx.x*256 + threadIdx.x;
  if (i < EE)   atomicAdd(&cg[dst[i]], 1);
  if (i < NINC){ atomicAdd(&cv[hv[i]], 1); atomicAdd(&ce[he[i]], 1); }
}

__global__ void k_invs(const int* __restrict__ cg, const int* __restrict__ cv,
                       const int* __restrict__ ce,
                       float* dinv, float* invd, float* invv, float* inve){
  int i = blockIdx.x*256 + threadIdx.x;
  if (i < NN){
    float d = 1.0f + (float)cg[i];     // self-loop included
    dinv[i] = rsqrtf(d);
    invd[i] = 1.0f / d;
    invv[i] = 1.0f / fmaxf((float)cv[i], 1.0f);
  }
  if (i < NEH) inve[i] = 1.0f / fmaxf((float)ce[i], 1.0f);
}

// exclusive scan, 256 elems/block (Hillis-Steele in LDS)
__global__ void k_scan1(const int* __restrict__ in, int* __restrict__ out,
                        int* __restrict__ bsum, int n){
  __shared__ int s[256];
  int t = threadIdx.x, i = blockIdx.x*256 + t;
  int v = (i < n) ? in[i] : 0;
  s[t] = v; __syncthreads();
  #pragma unroll
  for (int off = 1; off < 256; off <<= 1){
    int add = (t >= off) ? s[t-off] : 0;
    __syncthreads();
    s[t] += add;
    __syncthreads();
  }
  if (i < n) out[i] = s[t] - v;        // exclusive
  if (t == 255) bsum[blockIdx.x] = s[255];
}

__global__ void k_scan2(int* bsum, int nb){   // single block, nb <= 256
  __shared__ int s[256];
  int t = threadIdx.x;
  int v = (t < nb) ? bsum[t] : 0;
  s[t] = v; __syncthreads();
  #pragma unroll
  for (int off = 1; off < 256; off <<= 1){
    int add = (t >= off) ? s[t-off] : 0;
    __syncthreads();
    s[t] += add;
    __syncthreads();
  }
  if (t < nb) bsum[t] = s[t] - v;
}

__global__ void k_scan3(int* __restrict__ rp, int* __restrict__ cur,
                        const int* __restrict__ bsum, int n){
  int i = blockIdx.x*256 + threadIdx.x;
  if (i < n){ int v = rp[i] + bsum[blockIdx.x]; rp[i] = v; cur[i] = v; }
}

__global__ void k_fill_gcn(const int* __restrict__ src, const int* __restrict__ dst,
                           int* cur, int* __restrict__ csr){
  int i = blockIdx.x*256 + threadIdx.x;
  if (i < EE){ int p = atomicAdd(&cur[dst[i]], 1); csr[p] = src[i]; }
}

__global__ void k_fill_hg(const int* __restrict__ hv, const int* __restrict__ he,
                          int* cur_e, int* __restrict__ csr_e,
                          int* cur_v, int* __restrict__ csr_v){
  int i = blockIdx.x*256 + threadIdx.x;
  if (i < NINC){
    int v = hv[i], e = he[i];
    csr_e[atomicAdd(&cur_e[e], 1)] = v;
    csr_v[atomicAdd(&cur_v[v], 1)] = e;
  }
}

// ---------------- GEMM: C[M][NCOL] = A[M][KDIM] @ W[KDIM][NCOL] (+bias,relu) ----------------
template<int KDIM, int NCOL, bool AEXT>
__global__ __launch_bounds__(256) void k_gemm(const void* __restrict__ Av,
    const void* __restrict__ W, const void* __restrict__ bias,
    float* __restrict__ C, int M, int relu, const int* __restrict__ flag)
{
  constexpr int BM = 32, KC = 64;
  constexpr int CG  = NCOL/4;
  constexpr int RS  = 256/CG;
  constexpr int RPT = BM/RS;
  __shared__ float Ws[KC][NCOL];
  __shared__ float As[BM][KC+1];
  const int isbf = flag[0];
  const int tid = threadIdx.x;
  const int cg = tid % CG, rs = tid / CG;
  const int row0 = blockIdx.x * BM;
  float acc[RPT][4];
  #pragma unroll
  for (int r=0;r<RPT;r++){ acc[r][0]=acc[r][1]=acc[r][2]=acc[r][3]=0.f; }

  for (int kk=0; kk<KDIM; kk+=KC){
    for (int j=tid; j<KC*NCOL; j+=256)
      Ws[j/NCOL][j%NCOL] = ldf(W, (size_t)(kk + j/NCOL)*NCOL + (j%NCOL), isbf);
    for (int j=tid; j<BM*KC; j+=256){
      int r = j >> 6, k = j & 63;
      int row = row0 + r;
      float v = 0.f;
      if (row < M){
        if (AEXT) v = ldf(Av, (size_t)row*KDIM + kk + k, isbf);
        else      v = ((const float*)Av)[(size_t)row*KDIM + kk + k];
      }
      As[r][k] = v;
    }
    __syncthreads();
    #pragma unroll 8
    for (int k=0;k<KC;k++){
      float4 w = *(const float4*)&Ws[k][cg*4];
      #pragma unroll
      for (int rr=0; rr<RPT; rr++){
        float a = As[rs + rr*RS][k];
        acc[rr][0] = fmaf(a, w.x, acc[rr][0]);
        acc[rr][1] = fmaf(a, w.y, acc[rr][1]);
        acc[rr][2] = fmaf(a, w.z, acc[rr][2]);
        acc[rr][3] = fmaf(a, w.w, acc[rr][3]);
      }
    }
    __syncthreads();
  }
  float4 bv = make_float4(0.f,0.f,0.f,0.f);
  if (bias){
    bv.x = ldf(bias, cg*4+0, isbf); bv.y = ldf(bias, cg*4+1, isbf);
    bv.z = ldf(bias, cg*4+2, isbf); bv.w = ldf(bias, cg*4+3, isbf);
  }
  #pragma unroll
  for (int rr=0; rr<RPT; rr++){
    int row = row0 + rs + rr*RS;
    if (row < M){
      float o0=acc[rr][0]+bv.x, o1=acc[rr][1]+bv.y;
      float o2=acc[rr][2]+bv.z, o3=acc[rr][3]+bv.w;
      if (relu){ o0=fmaxf(o0,0.f); o1=fmaxf(o1,0.f); o2=fmaxf(o2,0.f); o3=fmaxf(o3,0.f); }
      *(float4*)&C[(size_t)row*NCOL + cg*4] = make_float4(o0,o1,o2,o3);
    }
  }
}

// ---------------- fused GCN gather: selfloop + edges + bias + relu ----------------
template<int F>
__global__ void k_gcn_gather(const int* __restrict__ rp, const int* __restrict__ cnt,
    const int* __restrict__ csr, const float* __restrict__ dinv,
    const float* __restrict__ invd, const float* __restrict__ h,
    const void* __restrict__ bias, float* __restrict__ out,
    int relu, const int* __restrict__ flag)
{
  int d = blockIdx.x, j = threadIdx.x;
  float acc = h[(size_t)d*F + j] * invd[d];       // self-loop term
  const float dd = dinv[d];
  int k = rp[d], e = k + cnt[d];
  for (; k < e; ++k){
    int s = csr[k];                                // same addr across block: broadcast
    acc = fmaf(h[(size_t)s*F + j], dinv[s]*dd, acc);
  }
  acc += ldf(bias, j, flag[0]);
  if (relu) acc = fmaxf(acc, 0.f);
  out[(size_t)d*F + j] = acc;
}

// ---------------- fused hypergraph gathers (mean) ----------------
template<int F>
__global__ void k_hg_e_gather(const int* __restrict__ rp, const int* __restrict__ cnt,
    const int* __restrict__ csr, const float* __restrict__ inve,
    const float* __restrict__ h, float* __restrict__ ef)
{
  int e = blockIdx.x, j = threadIdx.x;
  int k = rp[e], n = cnt[e];
  float acc = 0.f;
  for (int t = 0; t < n; ++t)
    acc += h[(size_t)csr[k+t]*F + j];
  ef[(size_t)e*F + j] = acc * inve[e];
}

template<int F>
__global__ void k_hg_v_gather(const int* __restrict__ rp, const int* __restrict__ cnt,
    const int* __restrict__ csr, const float* __restrict__ invv,
    const float* __restrict__ ef, float* __restrict__ out, int relu)
{
  int v = blockIdx.x, j = threadIdx.x;
  int k = rp[v], n = cnt[v];
  float acc = 0.f;
  for (int t = 0; t < n; ++t)
    acc += ef[(size_t)csr[k+t]*F + j];
  acc *= invv[v];
  if (relu) acc = fmaxf(acc, 0.f);
  out[(size_t)v*F + j] = acc;
}

// ---------------- embeds + row normalize ----------------
__global__ void k_embeds(const float* __restrict__ x2, const float* __restrict__ x4,
                         void* __restrict__ out, float* __restrict__ data,
                         const int* __restrict__ flag){
  int row  = blockIdx.x*4 + (threadIdx.x >> 6);
  int lane = threadIdx.x & 63;
  if (row >= NN) return;
  size_t idx = (size_t)row*64 + lane;
  float v = 0.5f*(x2[idx] + x4[idx]);
  float ss = v*v;
  #pragma unroll
  for (int off=32; off>0; off>>=1) ss += __shfl_xor(ss, off);
  float inv = rsqrtf(ss);
  data[idx] = v*inv;
  stf(out, EMB_OFF + idx, v, flag[0]);
}

// ---------------- clustering ----------------
__global__ void k_mu_init(const float* __restrict__ data, float* __restrict__ mu){
  int p = blockIdx.x*256 + threadIdx.x;
  if (p >= KCL*64) return;
  int k = p >> 6, f = p & 63;
  mu[p] = data[(size_t)k*(NN/KCL)*64 + f];   // init_idx = k*(N//K)
}

__global__ __launch_bounds__(128) void k_cluster_accum(const float* __restrict__ data,
    const float* __restrict__ mu, float* csum, float* cr, const int* nit, int iter)
{
  if (iter >= nit[0]) return;
  __shared__ float dt[128][65];
  __shared__ float rl[128][KCL];
  __shared__ float ms[KCL*64];
  int tid = threadIdx.x;
  int rowbase = blockIdx.x*128;
  for (int j=tid; j<KCL*64; j+=128) ms[j] = mu[j];
  for (int j=tid; j<128*64; j+=128){
    int rr = j>>6, f = j&63;
    int row = rowbase + rr;
    dt[rr][f] = (row<NN) ? data[(size_t)row*64+f] : 0.f;
  }
  __syncthreads();
  {
    int row = rowbase + tid;
    float dot[KCL];
    #pragma unroll
    for (int k2=0;k2<KCL;k2++) dot[k2]=0.f;
    for (int f=0; f<64; f++){
      float a = dt[tid][f];
      #pragma unroll
      for (int k2=0;k2<KCL;k2++) dot[k2] = fmaf(a, ms[k2*64+f], dot[k2]);
    }
    float m = -1e30f;
    #pragma unroll
    for (int k2=0;k2<KCL;k2++) m = fmaxf(m, 5.0f*dot[k2]);
    float s = 0.f, ev[KCL];
    #pragma unroll
    for (int k2=0;k2<KCL;k2++){ ev[k2] = expf(5.0f*dot[k2]-m); s += ev[k2]; }
    float inv = 1.0f/s;
    #pragma unroll
    for (int k2=0;k2<KCL;k2++) rl[tid][k2] = (row<NN) ? ev[k2]*inv : 0.f;
  }
  __syncthreads();
  for (int p=tid; p<KCL*64; p+=128){
    int k2 = p>>6, f = p&63;
    float acc = 0.f;
    for (int r2=0;r2<128;r2++) acc += rl[r2][k2]*dt[r2][f];
    unsafeAtomicAdd(&csum[p], acc);
  }
  if (tid < KCL){
    float acc = 0.f;
    for (int r2=0;r2<128;r2++) acc += rl[r2][tid];
    unsafeAtomicAdd(&cr[tid], acc);
  }
}

__global__ void k_mu_update(float* mu, float* csum, float* cr, const int* nit, int iter){
  if (iter >= nit[0]) return;
  int p = threadIdx.x;        // launched with exactly 640 threads
  float c = csum[p];
  float r = cr[p>>6];
  __syncthreads();
  mu[p] = c / r;
  csum[p] = 0.f;
  if (p < KCL) cr[p] = 0.f;
}

__global__ __launch_bounds__(128) void k_cluster_final(const float* __restrict__ data,
    const float* __restrict__ mu, void* __restrict__ out, const int* __restrict__ flag)
{
  __shared__ float dt[128][65];
  __shared__ float ms[KCL*64];
  int tid = threadIdx.x;
  int rowbase = blockIdx.x*128;
  for (int j=tid; j<KCL*64; j+=128) ms[j] = mu[j];
  for (int j=tid; j<128*64; j+=128){
    int rr = j>>6, f = j&63;
    int row = rowbase + rr;
    dt[rr][f] = (row<NN) ? data[(size_t)row*64+f] : 0.f;
  }
  __syncthreads();
  int row = rowbase + tid;
  if (row >= NN) return;
  int isbf = flag[0];
  float dot[KCL];
  #pragma unroll
  for (int k2=0;k2<KCL;k2++) dot[k2]=0.f;
  for (int f=0; f<64; f++){
    float a = dt[tid][f];
    #pragma unroll
    for (int k2=0;k2<KCL;k2++) dot[k2] = fmaf(a, ms[k2*64+f], dot[k2]);
  }
  float m = -1e30f;
  #pragma unroll
  for (int k2=0;k2<KCL;k2++) m = fmaxf(m, 5.0f*dot[k2]);
  float s = 0.f, ev[KCL];
  #pragma unroll
  for (int k2=0;k2<KCL;k2++){ ev[k2] = expf(5.0f*dot[k2]-m); s += ev[k2]; }
  float inv = 1.0f/s;
  #pragma unroll
  for (int k2=0;k2<KCL;k2++){
    stf(out, (size_t)D_OFF + (size_t)row*KCL + k2, dot[k2],     isbf);
    stf(out, (size_t)R_OFF + (size_t)row*KCL + k2, ev[k2]*inv,  isbf);
  }
}

__global__ void k_mu_out(const float* __restrict__ mu, void* __restrict__ out,
                         const int* __restrict__ flag){
  int p = blockIdx.x*256 + threadIdx.x;
  if (p < KCL*64) stf(out, MU_OFF + p, mu[p], flag[0]);
}

// ---------------- launch ----------------
extern "C" void kernel_launch(void* const* d_in, const int* in_sizes, int n_in,
                              void* d_out, int out_size, void* d_ws, size_t ws_size,
                              hipStream_t stream)
{
  const void* x   = d_in[0];
  const int*  ei  = (const int*)d_in[1];
  const int*  hv  = (const int*)d_in[2];
  const int*  he  = (const int*)d_in[3];
  const void* gW1 = d_in[4];
  const void* gb1 = d_in[5];
  const void* gW2 = d_in[6];
  const void* gb2 = d_in[7];
  const void* hW1 = d_in[8];
  const void* hb1 = d_in[9];
  const void* hW2 = d_in[10];
  const void* hb2 = d_in[11];
  const int*  nit = (const int*)d_in[12];

  float* ws = (float*)d_ws;
  size_t o = 0;
  float* BA   = ws + o; o += (size_t)NN*128;   // GEMM out / data
  float* BB   = ws + o; o += (size_t)NN*128;   // x1 / x2
  float* BC   = ws + o; o += (size_t)NN*128;   // x3 / x4
  float* BD   = ws + o; o += (size_t)NEH*128;  // e_feat
  float* dinv = ws + o; o += 50048;
  float* invd = ws + o; o += 50048;
  float* invv = ws + o; o += 50048;
  float* inve = ws + o; o += 10048;
  float* mu   = ws + o; o += 640;
  float* csum = ws + o; o += 640;
  float* cr   = ws + o; o += 64;
  int*   dflg = (int*)(ws + o); o += 16;
  // int region (CSR)
  int* ib = (int*)(ws + o);
  size_t io = 0;
  int* cg    = ib + io; io += NN;       // counts (contiguous for one memset)
  int* cv    = ib + io; io += NN;
  int* ce    = ib + io; io += NEH + 48;
  size_t cnt_ints = io;
  int* rp_g  = ib + io; io += NN;
  int* rp_v  = ib + io; io += NN;
  int* rp_e  = ib + io; io += NEH + 48;
  int* cu_g  = ib + io; io += NN;
  int* cu_v  = ib + io; io += NN;
  int* cu_e  = ib + io; io += NEH + 48;
  int* csr_g = ib + io; io += EE;
  int* csr_e = ib + io; io += NINC;     // per-hyperedge vertex lists
  int* csr_v = ib + io; io += NINC;     // per-vertex hyperedge lists
  int* bs_g  = ib + io; io += 256;
  int* bs_v  = ib + io; io += 256;
  int* bs_e  = ib + io; io += 256;

  const int* srcp = ei;
  const int* dstp = ei + EE;
  dim3 B(256);
  const int NBN = (NN + 255)/256;       // 196
  const int NBE = (NEH + 255)/256;      // 40

  // dtype detection
  k_detect<<<dim3(1), B, 0, stream>>>((const unsigned short*)x, dflg);

  // ---- CSR build ----
  hipMemsetAsync(cg, 0, cnt_ints*sizeof(int), stream);
  k_cnt <<<dim3((EE+255)/256), B, 0, stream>>>(dstp, hv, he, cg, cv, ce);
  k_invs<<<dim3(NBN), B, 0, stream>>>(cg, cv, ce, dinv, invd, invv, inve);
  // scans: gcn(dst), hv, he
  k_scan1<<<dim3(NBN), B, 0, stream>>>(cg, rp_g, bs_g, NN);
  k_scan2<<<dim3(1),   B, 0, stream>>>(bs_g, NBN);
  k_scan3<<<dim3(NBN), B, 0, stream>>>(rp_g, cu_g, bs_g, NN);
  k_scan1<<<dim3(NBN), B, 0, stream>>>(cv, rp_v, bs_v, NN);
  k_scan2<<<dim3(1),   B, 0, stream>>>(bs_v, NBN);
  k_scan3<<<dim3(NBN), B, 0, stream>>>(rp_v, cu_v, bs_v, NN);
  k_scan1<<<dim3(NBE), B, 0, stream>>>(ce, rp_e, bs_e, NEH);
  k_scan2<<<dim3(1),   B, 0, stream>>>(bs_e, NBE);
  k_scan3<<<dim3(NBE), B, 0, stream>>>(rp_e, cu_e, bs_e, NEH);
  k_fill_gcn<<<dim3((EE+255)/256),   B, 0, stream>>>(srcp, dstp, cu_g, csr_g);
  k_fill_hg <<<dim3((NINC+255)/256), B, 0, stream>>>(hv, he, cu_e, csr_e, cu_v, csr_v);

  const int NB = (NN + 31)/32;
  // ---- GCN layer 1: BA = x@gW1 ; x1(BB) = gather(BA) + gb1, relu ----
  k_gemm<256,128,true><<<dim3(NB), B, 0, stream>>>(x, gW1, nullptr, BA, NN, 0, dflg);
  k_gcn_gather<128><<<dim3(NN), dim3(128), 0, stream>>>(rp_g, cg, csr_g, dinv, invd,
                                                        BA, gb1, BB, 1, dflg);
  // ---- HGNNP layer 1: BA = x@hW1+hb1 ; ef(BD) ; x3(BC) relu ----
  k_gemm<256,128,true><<<dim3(NB), B, 0, stream>>>(x, hW1, hb1, BA, NN, 0, dflg);
  k_hg_e_gather<128><<<dim3(NEH), dim3(128), 0, stream>>>(rp_e, ce, csr_e, inve, BA, BD);
  k_hg_v_gather<128><<<dim3(NN),  dim3(128), 0, stream>>>(rp_v, cv, csr_v, invv, BD, BC, 1);

  // ---- GCN layer 2: BA = x1@gW2 ; x2(BB) = gather + gb2 ----
  k_gemm<128,64,false><<<dim3(NB), B, 0, stream>>>(BB, gW2, nullptr, BA, NN, 0, dflg);
  k_gcn_gather<64><<<dim3(NN), dim3(64), 0, stream>>>(rp_g, cg, csr_g, dinv, invd,
                                                      BA, gb2, BB, 0, dflg);
  // ---- HGNNP layer 2: BA = x3@hW2+hb2 ; ef(BD) ; x4(BC) ----
  k_gemm<128,64,false><<<dim3(NB), B, 0, stream>>>(BC, hW2, hb2, BA, NN, 0, dflg);
  k_hg_e_gather<64><<<dim3(NEH), dim3(64), 0, stream>>>(rp_e, ce, csr_e, inve, BA, BD);
  k_hg_v_gather<64><<<dim3(NN),  dim3(64), 0, stream>>>(rp_v, cv, csr_v, invv, BD, BC, 0);

  // ---- embeds (bf16/f32 out) + normalized rows -> data(BA) ----
  k_embeds<<<dim3((NN+3)/4), B, 0, stream>>>(BB, BC, d_out, BA, dflg);

  // ---- clustering ----
  k_mu_init<<<dim3(3), B, 0, stream>>>(BA, mu);
  hipMemsetAsync(csum, 0, (640+64)*4, stream);
  const int CB = (NN + 127)/128;
  for (int it = 0; it < 4; ++it){   // gated by iter < *num_iter (setup: 1)
    k_cluster_accum<<<dim3(CB), dim3(128), 0, stream>>>(BA, mu, csum, cr, nit, it);
    k_mu_update    <<<dim3(1),  dim3(640), 0, stream>>>(mu, csum, cr, nit, it);
  }
  k_cluster_final<<<dim3(CB), dim3(128), 0, stream>>>(BA, mu, d_out, dflg);
  k_mu_out       <<<dim3(3),  B, 0, stream>>>(mu, d_out, dflg);
}

// Round 6
// 634.234 us; speedup vs baseline: 5.7644x; 1.3604x over previous
//
#include <hip/hip_runtime.h>
#include <hip/hip_bf16.h>

// HGNNP_GCN + ClusterNet forward, MI355X (round 6).
// R5 counters: k_gemm 168-195us each, VALUBusy 21%, occupancy 26%, HBM 3.4%
// -> latency-bound vector GEMM (scalar LDS reads, 41KB LDS caps residency).
// This round: GEMM restructured to BM=64/KC=32 with float4 register tiles on
// both A and W (12 LDS instrs per 128 FMAs), LDS ~25KB. Math unchanged (f32).

#define NN   50000   // nodes
#define EE   800000  // directed edges
#define NINC 200000  // incidence entries
#define NEH  10000   // hyperedges
#define KCL  10      // clusters

// output element offsets (flat concat: mu | r | embeds | dist)
#define MU_OFF  0
#define R_OFF   640
#define EMB_OFF 500640
#define D_OFF   3700640

typedef __hip_bfloat16 bf16;

__device__ __forceinline__ float b2f(bf16 v){ return __bfloat162float(v); }
__device__ __forceinline__ bf16 f2b(float f){
  unsigned u = __float_as_uint(f);
  unsigned r = (u + 0x7fffu + ((u >> 16) & 1u)) >> 16;  // RNE to bf16
  bf16 h;
  reinterpret_cast<unsigned short&>(h) = (unsigned short)r;
  return h;
}
// external-float load/store, dtype chosen by uniform runtime flag
__device__ __forceinline__ float ldf(const void* p, size_t i, int isbf){
  return isbf ? b2f(((const bf16*)p)[i]) : ((const float*)p)[i];
}
__device__ __forceinline__ void stf(void* p, size_t i, float v, int isbf){
  if (isbf) ((bf16*)p)[i] = f2b(v);
  else      ((float*)p)[i] = v;
}

// ---------------- dtype detector ----------------
__global__ void k_detect(const unsigned short* __restrict__ xr, int* flag){
  __shared__ int bad;
  if (threadIdx.x == 0) bad = 0;
  __syncthreads();
  for (int i = threadIdx.x; i < 4096; i += 256){
    int e = (xr[i] >> 7) & 0xFF;
    if (e >= 0xEF) bad = 1;     // f32 low-halves have random exponents
  }
  __syncthreads();
  if (threadIdx.x == 0) *flag = bad ? 0 : 1;   // 1 = bf16, 0 = f32
}

// ---------------- CSR build: count / scan / fill ----------------
__global__ void k_cnt(const int* __restrict__ dst, const int* __restrict__ hv,
                      const int* __restrict__ he, int* cg, int* cv, int* ce){
  int i = blockIdx.x*256 + threadIdx.x;
  if (i < EE)   atomicAdd(&cg[dst[i]], 1);
  if (i < NINC){ atomicAdd(&cv[hv[i]], 1); atomicAdd(&ce[he[i]], 1); }
}

__global__ void k_invs(const int* __restrict__ cg, const int* __restrict__ cv,
                       const int* __restrict__ ce,
                       float* dinv, float* invd, float* invv, float* inve){
  int i = blockIdx.x*256 + threadIdx.x;
  if (i < NN){
    float d = 1.0f + (float)cg[i];     // self-loop included
    dinv[i] = rsqrtf(d);
    invd[i] = 1.0f / d;
    invv[i] = 1.0f / fmaxf((float)cv[i], 1.0f);
  }
  if (i < NEH) inve[i] = 1.0f / fmaxf((float)ce[i], 1.0f);
}

// exclusive scan, 256 elems/block (Hillis-Steele in LDS)
__global__ void k_scan1(const int* __restrict__ in, int* __restrict__ out,
                        int* __restrict__ bsum, int n){
  __shared__ int s[256];
  int t = threadIdx.x, i = blockIdx.x*256 + t;
  int v = (i < n) ? in[i] : 0;
  s[t] = v; __syncthreads();
  #pragma unroll
  for (int off = 1; off < 256; off <<= 1){
    int add = (t >= off) ? s[t-off] : 0;
    __syncthreads();
    s[t] += add;
    __syncthreads();
  }
  if (i < n) out[i] = s[t] - v;        // exclusive
  if (t == 255) bsum[blockIdx.x] = s[255];
}

__global__ void k_scan2(int* bsum, int nb){   // single block, nb <= 256
  __shared__ int s[256];
  int t = threadIdx.x;
  int v = (t < nb) ? bsum[t] : 0;
  s[t] = v; __syncthreads();
  #pragma unroll
  for (int off = 1; off < 256; off <<= 1){
    int add = (t >= off) ? s[t-off] : 0;
    __syncthreads();
    s[t] += add;
    __syncthreads();
  }
  if (t < nb) bsum[t] = s[t] - v;
}

__global__ void k_scan3(int* __restrict__ rp, int* __restrict__ cur,
                        const int* __restrict__ bsum, int n){
  int i = blockIdx.x*256 + threadIdx.x;
  if (i < n){ int v = rp[i] + bsum[blockIdx.x]; rp[i] = v; cur[i] = v; }
}

__global__ void k_fill_gcn(const int* __restrict__ src, const int* __restrict__ dst,
                           int* cur, int* __restrict__ csr){
  int i = blockIdx.x*256 + threadIdx.x;
  if (i < EE){ int p = atomicAdd(&cur[dst[i]], 1); csr[p] = src[i]; }
}

__global__ void k_fill_hg(const int* __restrict__ hv, const int* __restrict__ he,
                          int* cur_e, int* __restrict__ csr_e,
                          int* cur_v, int* __restrict__ csr_v){
  int i = blockIdx.x*256 + threadIdx.x;
  if (i < NINC){
    int v = hv[i], e = he[i];
    csr_e[atomicAdd(&cur_e[e], 1)] = v;
    csr_v[atomicAdd(&cur_v[v], 1)] = e;
  }
}

// ---------------- GEMM v2: C[M][NCOL] = A[M][KDIM] @ W[KDIM][NCOL] ----------------
// 256 threads, BM=64 rows/block, KC=32 k-chunk. Per-thread register tile:
// RPT rows x 4 cols, inner step consumes 4 k's via float4 LDS reads on A and W.
template<int KDIM, int NCOL, bool AEXT>
__global__ __launch_bounds__(256) void k_gemmv2(const void* __restrict__ Av,
    const void* __restrict__ W, const void* __restrict__ bias,
    float* __restrict__ C, int M, int relu, const int* __restrict__ flag)
{
  constexpr int BM = 64, KC = 32;
  constexpr int CG  = NCOL/4;      // col groups (float4)
  constexpr int RS  = 256/CG;      // row slots
  constexpr int RPT = BM/RS;       // rows per thread (128->8, 64->4)
  __shared__ __align__(16) float Ws[KC][NCOL];      // no pad (measured 0-conflict pattern)
  __shared__ __align__(16) float As[BM][KC+4];      // 36-word rows, 16B-aligned
  const int isbf = flag[0];
  const int tid = threadIdx.x;
  const int cg = tid % CG, rs = tid / CG;
  const int row0 = blockIdx.x * BM;

  float acc[RPT][4];
  #pragma unroll
  for (int r=0;r<RPT;r++){ acc[r][0]=acc[r][1]=acc[r][2]=acc[r][3]=0.f; }

  float4* Ws4 = (float4*)&Ws[0][0];
  const float* Af = (const float*)Av;
  const bf16*  Ab = (const bf16*)Av;

  for (int kk = 0; kk < KDIM; kk += KC){
    // stage W chunk (contiguous KC*NCOL block)
    #pragma unroll
    for (int s = tid; s < KC*NCOL/4; s += 256){
      if (isbf){
        const bf16* wp = (const bf16*)W + (size_t)kk*NCOL + s*4;
        Ws4[s] = make_float4(b2f(wp[0]), b2f(wp[1]), b2f(wp[2]), b2f(wp[3]));
      } else {
        Ws4[s] = ((const float4*)((const float*)W + (size_t)kk*NCOL))[s];
      }
    }
    // stage A tile: BM x KC
    #pragma unroll
    for (int s = tid; s < BM*KC/4; s += 256){
      int r = s / (KC/4), kq = s % (KC/4);
      int grow = row0 + r;
      float4 v = make_float4(0.f,0.f,0.f,0.f);
      if (grow < M){
        size_t off = (size_t)grow*KDIM + kk + kq*4;
        if (AEXT && isbf){
          const bf16* ap = Ab + off;
          v = make_float4(b2f(ap[0]), b2f(ap[1]), b2f(ap[2]), b2f(ap[3]));
        } else {
          v = *(const float4*)(Af + off);
        }
      }
      *(float4*)&As[r][kq*4] = v;
    }
    __syncthreads();

    #pragma unroll
    for (int k4 = 0; k4 < KC/4; ++k4){
      float4 w0 = *(const float4*)&Ws[k4*4+0][cg*4];
      float4 w1 = *(const float4*)&Ws[k4*4+1][cg*4];
      float4 w2 = *(const float4*)&Ws[k4*4+2][cg*4];
      float4 w3 = *(const float4*)&Ws[k4*4+3][cg*4];
      #pragma unroll
      for (int rr = 0; rr < RPT; ++rr){
        float4 a = *(const float4*)&As[rs + rr*RS][k4*4];
        acc[rr][0] = fmaf(a.x, w0.x, acc[rr][0]);
        acc[rr][1] = fmaf(a.x, w0.y, acc[rr][1]);
        acc[rr][2] = fmaf(a.x, w0.z, acc[rr][2]);
        acc[rr][3] = fmaf(a.x, w0.w, acc[rr][3]);
        acc[rr][0] = fmaf(a.y, w1.x, acc[rr][0]);
        acc[rr][1] = fmaf(a.y, w1.y, acc[rr][1]);
        acc[rr][2] = fmaf(a.y, w1.z, acc[rr][2]);
        acc[rr][3] = fmaf(a.y, w1.w, acc[rr][3]);
        acc[rr][0] = fmaf(a.z, w2.x, acc[rr][0]);
        acc[rr][1] = fmaf(a.z, w2.y, acc[rr][1]);
        acc[rr][2] = fmaf(a.z, w2.z, acc[rr][2]);
        acc[rr][3] = fmaf(a.z, w2.w, acc[rr][3]);
        acc[rr][0] = fmaf(a.w, w3.x, acc[rr][0]);
        acc[rr][1] = fmaf(a.w, w3.y, acc[rr][1]);
        acc[rr][2] = fmaf(a.w, w3.z, acc[rr][2]);
        acc[rr][3] = fmaf(a.w, w3.w, acc[rr][3]);
      }
    }
    __syncthreads();
  }

  float4 bv = make_float4(0.f,0.f,0.f,0.f);
  if (bias){
    bv.x = ldf(bias, cg*4+0, isbf); bv.y = ldf(bias, cg*4+1, isbf);
    bv.z = ldf(bias, cg*4+2, isbf); bv.w = ldf(bias, cg*4+3, isbf);
  }
  #pragma unroll
  for (int rr = 0; rr < RPT; ++rr){
    int row = row0 + rs + rr*RS;
    if (row < M){
      float o0=acc[rr][0]+bv.x, o1=acc[rr][1]+bv.y;
      float o2=acc[rr][2]+bv.z, o3=acc[rr][3]+bv.w;
      if (relu){ o0=fmaxf(o0,0.f); o1=fmaxf(o1,0.f); o2=fmaxf(o2,0.f); o3=fmaxf(o3,0.f); }
      *(float4*)&C[(size_t)row*NCOL + cg*4] = make_float4(o0,o1,o2,o3);
    }
  }
}

// ---------------- fused GCN gather: selfloop + edges + bias + relu ----------------
template<int F>
__global__ void k_gcn_gather(const int* __restrict__ rp, const int* __restrict__ cnt,
    const int* __restrict__ csr, const float* __restrict__ dinv,
    const float* __restrict__ invd, const float* __restrict__ h,
    const void* __restrict__ bias, float* __restrict__ out,
    int relu, const int* __restrict__ flag)
{
  int d = blockIdx.x, j = threadIdx.x;
  float acc = h[(size_t)d*F + j] * invd[d];       // self-loop term
  const float dd = dinv[d];
  int k = rp[d], e = k + cnt[d];
  for (; k < e; ++k){
    int s = csr[k];                                // same addr across block: broadcast
    acc = fmaf(h[(size_t)s*F + j], dinv[s]*dd, acc);
  }
  acc += ldf(bias, j, flag[0]);
  if (relu) acc = fmaxf(acc, 0.f);
  out[(size_t)d*F + j] = acc;
}

// ---------------- fused hypergraph gathers (mean) ----------------
template<int F>
__global__ void k_hg_e_gather(const int* __restrict__ rp, const int* __restrict__ cnt,
    const int* __restrict__ csr, const float* __restrict__ inve,
    const float* __restrict__ h, float* __restrict__ ef)
{
  int e = blockIdx.x, j = threadIdx.x;
  int k = rp[e], n = cnt[e];
  float acc = 0.f;
  for (int t = 0; t < n; ++t)
    acc += h[(size_t)csr[k+t]*F + j];
  ef[(size_t)e*F + j] = acc * inve[e];
}

template<int F>
__global__ void k_hg_v_gather(const int* __restrict__ rp, const int* __restrict__ cnt,
    const int* __restrict__ csr, const float* __restrict__ invv,
    const float* __restrict__ ef, float* __restrict__ out, int relu)
{
  int v = blockIdx.x, j = threadIdx.x;
  int k = rp[v], n = cnt[v];
  float acc = 0.f;
  for (int t = 0; t < n; ++t)
    acc += ef[(size_t)csr[k+t]*F + j];
  acc *= invv[v];
  if (relu) acc = fmaxf(acc, 0.f);
  out[(size_t)v*F + j] = acc;
}

// ---------------- embeds + row normalize ----------------
__global__ void k_embeds(const float* __restrict__ x2, const float* __restrict__ x4,
                         void* __restrict__ out, float* __restrict__ data,
                         const int* __restrict__ flag){
  int row  = blockIdx.x*4 + (threadIdx.x >> 6);
  int lane = threadIdx.x & 63;
  if (row >= NN) return;
  size_t idx = (size_t)row*64 + lane;
  float v = 0.5f*(x2[idx] + x4[idx]);
  float ss = v*v;
  #pragma unroll
  for (int off=32; off>0; off>>=1) ss += __shfl_xor(ss, off);
  float inv = rsqrtf(ss);
  data[idx] = v*inv;
  stf(out, EMB_OFF + idx, v, flag[0]);
}

// ---------------- clustering ----------------
__global__ void k_mu_init(const float* __restrict__ data, float* __restrict__ mu){
  int p = blockIdx.x*256 + threadIdx.x;
  if (p >= KCL*64) return;
  int k = p >> 6, f = p & 63;
  mu[p] = data[(size_t)k*(NN/KCL)*64 + f];   // init_idx = k*(N//K)
}

__global__ __launch_bounds__(128) void k_cluster_accum(const float* __restrict__ data,
    const float* __restrict__ mu, float* csum, float* cr, const int* nit, int iter)
{
  if (iter >= nit[0]) return;
  __shared__ float dt[128][65];
  __shared__ float rl[128][KCL];
  __shared__ float ms[KCL*64];
  int tid = threadIdx.x;
  int rowbase = blockIdx.x*128;
  for (int j=tid; j<KCL*64; j+=128) ms[j] = mu[j];
  for (int j=tid; j<128*64; j+=128){
    int rr = j>>6, f = j&63;
    int row = rowbase + rr;
    dt[rr][f] = (row<NN) ? data[(size_t)row*64+f] : 0.f;
  }
  __syncthreads();
  {
    int row = rowbase + tid;
    float dot[KCL];
    #pragma unroll
    for (int k2=0;k2<KCL;k2++) dot[k2]=0.f;
    for (int f=0; f<64; f++){
      float a = dt[tid][f];
      #pragma unroll
      for (int k2=0;k2<KCL;k2++) dot[k2] = fmaf(a, ms[k2*64+f], dot[k2]);
    }
    float m = -1e30f;
    #pragma unroll
    for (int k2=0;k2<KCL;k2++) m = fmaxf(m, 5.0f*dot[k2]);
    float s = 0.f, ev[KCL];
    #pragma unroll
    for (int k2=0;k2<KCL;k2++){ ev[k2] = expf(5.0f*dot[k2]-m); s += ev[k2]; }
    float inv = 1.0f/s;
    #pragma unroll
    for (int k2=0;k2<KCL;k2++) rl[tid][k2] = (row<NN) ? ev[k2]*inv : 0.f;
  }
  __syncthreads();
  for (int p=tid; p<KCL*64; p+=128){
    int k2 = p>>6, f = p&63;
    float acc = 0.f;
    for (int r2=0;r2<128;r2++) acc += rl[r2][k2]*dt[r2][f];
    unsafeAtomicAdd(&csum[p], acc);
  }
  if (tid < KCL){
    float acc = 0.f;
    for (int r2=0;r2<128;r2++) acc += rl[r2][tid];
    unsafeAtomicAdd(&cr[tid], acc);
  }
}

__global__ void k_mu_update(float* mu, float* csum, float* cr, const int* nit, int iter){
  if (iter >= nit[0]) return;
  int p = threadIdx.x;        // launched with exactly 640 threads
  float c = csum[p];
  float r = cr[p>>6];
  __syncthreads();
  mu[p] = c / r;
  csum[p] = 0.f;
  if (p < KCL) cr[p] = 0.f;
}

__global__ __launch_bounds__(128) void k_cluster_final(const float* __restrict__ data,
    const float* __restrict__ mu, void* __restrict__ out, const int* __restrict__ flag)
{
  __shared__ float dt[128][65];
  __shared__ float ms[KCL*64];
  int tid = threadIdx.x;
  int rowbase = blockIdx.x*128;
  for (int j=tid; j<KCL*64; j+=128) ms[j] = mu[j];
  for (int j=tid; j<128*64; j+=128){
    int rr = j>>6, f = j&63;
    int row = rowbase + rr;
    dt[rr][f] = (row<NN) ? data[(size_t)row*64+f] : 0.f;
  }
  __syncthreads();
  int row = rowbase + tid;
  if (row >= NN) return;
  int isbf = flag[0];
  float dot[KCL];
  #pragma unroll
  for (int k2=0;k2<KCL;k2++) dot[k2]=0.f;
  for (int f=0; f<64; f++){
    float a = dt[tid][f];
    #pragma unroll
    for (int k2=0;k2<KCL;k2++) dot[k2] = fmaf(a, ms[k2*64+f], dot[k2]);
  }
  float m = -1e30f;
  #pragma unroll
  for (int k2=0;k2<KCL;k2++) m = fmaxf(m, 5.0f*dot[k2]);
  float s = 0.f, ev[KCL];
  #pragma unroll
  for (int k2=0;k2<KCL;k2++){ ev[k2] = expf(5.0f*dot[k2]-m); s += ev[k2]; }
  float inv = 1.0f/s;
  #pragma unroll
  for (int k2=0;k2<KCL;k2++){
    stf(out, (size_t)D_OFF + (size_t)row*KCL + k2, dot[k2],     isbf);
    stf(out, (size_t)R_OFF + (size_t)row*KCL + k2, ev[k2]*inv,  isbf);
  }
}

__global__ void k_mu_out(const float* __restrict__ mu, void* __restrict__ out,
                         const int* __restrict__ flag){
  int p = blockIdx.x*256 + threadIdx.x;
  if (p < KCL*64) stf(out, MU_OFF + p, mu[p], flag[0]);
}

// ---------------- launch ----------------
extern "C" void kernel_launch(void* const* d_in, const int* in_sizes, int n_in,
                              void* d_out, int out_size, void* d_ws, size_t ws_size,
                              hipStream_t stream)
{
  const void* x   = d_in[0];
  const int*  ei  = (const int*)d_in[1];
  const int*  hv  = (const int*)d_in[2];
  const int*  he  = (const int*)d_in[3];
  const void* gW1 = d_in[4];
  const void* gb1 = d_in[5];
  const void* gW2 = d_in[6];
  const void* gb2 = d_in[7];
  const void* hW1 = d_in[8];
  const void* hb1 = d_in[9];
  const void* hW2 = d_in[10];
  const void* hb2 = d_in[11];
  const int*  nit = (const int*)d_in[12];

  float* ws = (float*)d_ws;
  size_t o = 0;
  float* BA   = ws + o; o += (size_t)NN*128;   // GEMM out / data
  float* BB   = ws + o; o += (size_t)NN*128;   // x1 / x2
  float* BC   = ws + o; o += (size_t)NN*128;   // x3 / x4
  float* BD   = ws + o; o += (size_t)NEH*128;  // e_feat
  float* dinv = ws + o; o += 50048;
  float* invd = ws + o; o += 50048;
  float* invv = ws + o; o += 50048;
  float* inve = ws + o; o += 10048;
  float* mu   = ws + o; o += 640;
  float* csum = ws + o; o += 640;
  float* cr   = ws + o; o += 64;
  int*   dflg = (int*)(ws + o); o += 16;
  // int region (CSR)
  int* ib = (int*)(ws + o);
  size_t io = 0;
  int* cg    = ib + io; io += NN;       // counts (contiguous for one memset)
  int* cv    = ib + io; io += NN;
  int* ce    = ib + io; io += NEH + 48;
  size_t cnt_ints = io;
  int* rp_g  = ib + io; io += NN;
  int* rp_v  = ib + io; io += NN;
  int* rp_e  = ib + io; io += NEH + 48;
  int* cu_g  = ib + io; io += NN;
  int* cu_v  = ib + io; io += NN;
  int* cu_e  = ib + io; io += NEH + 48;
  int* csr_g = ib + io; io += EE;
  int* csr_e = ib + io; io += NINC;     // per-hyperedge vertex lists
  int* csr_v = ib + io; io += NINC;     // per-vertex hyperedge lists
  int* bs_g  = ib + io; io += 256;
  int* bs_v  = ib + io; io += 256;
  int* bs_e  = ib + io; io += 256;

  const int* srcp = ei;
  const int* dstp = ei + EE;
  dim3 B(256);
  const int NBN = (NN + 255)/256;       // 196
  const int NBE = (NEH + 255)/256;      // 40

  // dtype detection
  k_detect<<<dim3(1), B, 0, stream>>>((const unsigned short*)x, dflg);

  // ---- CSR build ----
  hipMemsetAsync(cg, 0, cnt_ints*sizeof(int), stream);
  k_cnt <<<dim3((EE+255)/256), B, 0, stream>>>(dstp, hv, he, cg, cv, ce);
  k_invs<<<dim3(NBN), B, 0, stream>>>(cg, cv, ce, dinv, invd, invv, inve);
  // scans: gcn(dst), hv, he
  k_scan1<<<dim3(NBN), B, 0, stream>>>(cg, rp_g, bs_g, NN);
  k_scan2<<<dim3(1),   B, 0, stream>>>(bs_g, NBN);
  k_scan3<<<dim3(NBN), B, 0, stream>>>(rp_g, cu_g, bs_g, NN);
  k_scan1<<<dim3(NBN), B, 0, stream>>>(cv, rp_v, bs_v, NN);
  k_scan2<<<dim3(1),   B, 0, stream>>>(bs_v, NBN);
  k_scan3<<<dim3(NBN), B, 0, stream>>>(rp_v, cu_v, bs_v, NN);
  k_scan1<<<dim3(NBE), B, 0, stream>>>(ce, rp_e, bs_e, NEH);
  k_scan2<<<dim3(1),   B, 0, stream>>>(bs_e, NBE);
  k_scan3<<<dim3(NBE), B, 0, stream>>>(rp_e, cu_e, bs_e, NEH);
  k_fill_gcn<<<dim3((EE+255)/256),   B, 0, stream>>>(srcp, dstp, cu_g, csr_g);
  k_fill_hg <<<dim3((NINC+255)/256), B, 0, stream>>>(hv, he, cu_e, csr_e, cu_v, csr_v);

  const int NB = (NN + 63)/64;          // 782 blocks (BM=64)
  // ---- GCN layer 1: BA = x@gW1 ; x1(BB) = gather(BA) + gb1, relu ----
  k_gemmv2<256,128,true><<<dim3(NB), B, 0, stream>>>(x, gW1, nullptr, BA, NN, 0, dflg);
  k_gcn_gather<128><<<dim3(NN), dim3(128), 0, stream>>>(rp_g, cg, csr_g, dinv, invd,
                                                        BA, gb1, BB, 1, dflg);
  // ---- HGNNP layer 1: BA = x@hW1+hb1 ; ef(BD) ; x3(BC) relu ----
  k_gemmv2<256,128,true><<<dim3(NB), B, 0, stream>>>(x, hW1, hb1, BA, NN, 0, dflg);
  k_hg_e_gather<128><<<dim3(NEH), dim3(128), 0, stream>>>(rp_e, ce, csr_e, inve, BA, BD);
  k_hg_v_gather<128><<<dim3(NN),  dim3(128), 0, stream>>>(rp_v, cv, csr_v, invv, BD, BC, 1);

  // ---- GCN layer 2: BA = x1@gW2 ; x2(BB) = gather + gb2 ----
  k_gemmv2<128,64,false><<<dim3(NB), B, 0, stream>>>(BB, gW2, nullptr, BA, NN, 0, dflg);
  k_gcn_gather<64><<<dim3(NN), dim3(64), 0, stream>>>(rp_g, cg, csr_g, dinv, invd,
                                                      BA, gb2, BB, 0, dflg);
  // ---- HGNNP layer 2: BA = x3@hW2+hb2 ; ef(BD) ; x4(BC) ----
  k_gemmv2<128,64,false><<<dim3(NB), B, 0, stream>>>(BC, hW2, hb2, BA, NN, 0, dflg);
  k_hg_e_gather<64><<<dim3(NEH), dim3(64), 0, stream>>>(rp_e, ce, csr_e, inve, BA, BD);
  k_hg_v_gather<64><<<dim3(NN),  dim3(64), 0, stream>>>(rp_v, cv, csr_v, invv, BD, BC, 0);

  // ---- embeds (f32/bf16 out) + normalized rows -> data(BA) ----
  k_embeds<<<dim3((NN+3)/4), B, 0, stream>>>(BB, BC, d_out, BA, dflg);

  // ---- clustering ----
  k_mu_init<<<dim3(3), B, 0, stream>>>(BA, mu);
  hipMemsetAsync(csum, 0, (640+64)*4, stream);
  const int CB = (NN + 127)/128;
  for (int it = 0; it < 4; ++it){   // gated by iter < *num_iter (setup: 1)
    k_cluster_accum<<<dim3(CB), dim3(128), 0, stream>>>(BA, mu, csum, cr, nit, it);
    k_mu_update    <<<dim3(1),  dim3(640), 0, stream>>>(mu, csum, cr, nit, it);
  }
  k_cluster_final<<<dim3(CB), dim3(128), 0, stream>>>(BA, mu, d_out, dflg);
  k_mu_out       <<<dim3(3),  B, 0, stream>>>(mu, d_out, dflg);
}